// Round 2
// baseline (33310.300 us; speedup 1.0000x reference)
//
#include <hip/hip_runtime.h>

// Problem constants (fixed by the reference)
#define NN 50000
#define TT 200
#define HH 128
#define EE 1600000

typedef _Float16 f16x8 __attribute__((ext_vector_type(8)));
typedef float f32x4 __attribute__((ext_vector_type(4)));

__device__ __forceinline__ float sigf(float x) {
    // 1/(1+e^-x); exp overflow saturates correctly through rcp (inf->0, 0->1)
    return __builtin_amdgcn_rcpf(1.f + __expf(-x));
}
__device__ __forceinline__ float tanhf_(float x) {
    // 1 - 2/(e^{2x}+1); exact saturation at +/-1 for large |x|
    return 1.f - 2.f * __builtin_amdgcn_rcpf(__expf(2.f * x) + 1.f);
}
__device__ __forceinline__ unsigned short f2h_bits(float x) {
    _Float16 h = (_Float16)x;
    union { _Float16 h; unsigned short u; } cv; cv.h = h; return cv.u;
}

// ---------------------------------------------------------------------------
// Weight packing: W is (512,128) row-major (PyTorch [4H, H]).
// MFMA-16x16x32 B-fragment order: tile jn (0..31 over gate-cols), chunk kk (0..3):
// out[(jn*4+kk)*512 + L*8 + i] = W[jn*16 + (L&15)][kk*32 + (L>>4)*8 + i]  (f16)
// ---------------------------------------------------------------------------
__global__ void pack_w(const float* __restrict__ W, unsigned short* __restrict__ out) {
    int tile = blockIdx.x;          // jn*4 + kk
    int jn = tile >> 2, kk = tile & 3;
    int L = threadIdx.x;            // 0..63
    int n = jn * 16 + (L & 15);
    int k0 = kk * 32 + (L >> 4) * 8;
    unsigned short* dst = out + (size_t)tile * 512 + L * 8;
#pragma unroll
    for (int i = 0; i < 8; ++i) dst[i] = f2h_bits(W[n * 128 + k0 + i]);
}

__global__ void bias_prep(const float* __restrict__ bih0, const float* __restrict__ bhh0,
                          const float* __restrict__ bih1, const float* __restrict__ bhh1,
                          const float* __restrict__ wih0,
                          float* __restrict__ b0g, float* __restrict__ b1g, float* __restrict__ wxg) {
    int i = blockIdx.x * 256 + threadIdx.x;
    if (i < 512) {
        b0g[i] = bih0[i] + bhh0[i];
        b1g[i] = bih1[i] + bhh1[i];
        wxg[i] = wih0[i];
    }
}

// lightcurve [N][T] -> xT [T][N]
__global__ void transpose_lc(const float* __restrict__ lc, float* __restrict__ xT) {
    __shared__ float tile[32][33];
    int tx = threadIdx.x, ty = threadIdx.y;    // 32 x 8
    int n0 = blockIdx.y * 32, t0 = blockIdx.x * 32;
#pragma unroll
    for (int i = 0; i < 32; i += 8) {
        int n = n0 + ty + i, t = t0 + tx;
        if (n < NN && t < TT) tile[ty + i][tx] = lc[(size_t)n * TT + t];
    }
    __syncthreads();
#pragma unroll
    for (int i = 0; i < 32; i += 8) {
        int t = t0 + ty + i, n = n0 + tx;
        if (n < NN && t < TT) xT[(size_t)t * NN + n] = tile[tx][ty + i];
    }
}

// ---------------------------------------------------------------------------
// Fused 2-layer LSTM, gate-phased to cap live registers.
// Block = 256 threads (4 waves), 64 nodes, all 200 steps.
// Wave w owns output cols j = {w*16+col, (w+4)*16+col}. Per (q, gate-phase) a
// K-loop accumulates 4 row-tiles (16 acc regs); phases F -> I*G -> O update
// c incrementally so at most 32 acc regs are live. A-frags re-read from LDS
// per phase (LDS pipe ~3% of MFMA budget). h states in LDS f16, c in VGPRs.
// ---------------------------------------------------------------------------
__global__ __launch_bounds__(256, 3) void lstm_kernel(
    const float* __restrict__ xT,
    const unsigned short* __restrict__ w0p,
    const unsigned short* __restrict__ w1ip,
    const unsigned short* __restrict__ w1hp,
    const float* __restrict__ b0g, const float* __restrict__ b1g,
    const float* __restrict__ wxg,
    float* __restrict__ h2out) {
    __shared__ unsigned short h1s[64][136];
    __shared__ unsigned short h2s[64][136];
    __shared__ float xs[64];
    __shared__ float b0s[512], b1s[512], wxs[512];

    const int tid = threadIdx.x;
    const int w = tid >> 6;
    const int lane = tid & 63;
    const int col = lane & 15;
    const int quad = lane >> 4;
    const int n0 = blockIdx.x * 64;

    for (int i = tid; i < 64 * 136; i += 256) { (&h1s[0][0])[i] = 0; (&h2s[0][0])[i] = 0; }
    for (int i = tid; i < 512; i += 256) { b0s[i] = b0g[i]; b1s[i] = b1g[i]; wxs[i] = wxg[i]; }

    float c1[2][4][4] = {};
    float c2[2][4][4] = {};
    float h1v[2][4][4];
    float h2v[2][4][4];

    // K-loop over one 16-col gate tile: acc[rt] += h-tile(rt) x W-tile
    auto mm4 = [&](const unsigned short* __restrict__ wp,
                   const unsigned short (*hs)[136], int tile, f32x4 acc[4]) {
        const unsigned short* wb = wp + (size_t)tile * 2048 + lane * 8;
#pragma unroll
        for (int kk = 0; kk < 4; ++kk) {
            f16x8 b = *reinterpret_cast<const f16x8*>(wb + kk * 512);
#pragma unroll
            for (int rt = 0; rt < 4; ++rt) {
                f16x8 a = *reinterpret_cast<const f16x8*>(&hs[rt * 16 + col][kk * 32 + quad * 8]);
                acc[rt] = __builtin_amdgcn_mfma_f32_16x16x32_f16(a, b, acc[rt], 0, 0, 0);
            }
        }
    };

#pragma unroll 1
    for (int t = 0; t < TT; ++t) {
        if (tid < 64) {
            int n = n0 + tid;
            xs[tid] = (n < NN) ? xT[(size_t)t * NN + n] : 0.f;
        }
        __syncthreads();   // xs + h2s writes (t-1) visible

        // ---------------- layer 0: gates = h1 @ Whh0^T + x*wih0 + b0
#pragma unroll
        for (int q = 0; q < 2; ++q) {
            const int jt = w + 4 * q;
            const int j = jt * 16 + col;
            // phase F (gate idx 1)
            {
                f32x4 acc[4];
#pragma unroll
                for (int rt = 0; rt < 4; ++rt) acc[rt] = 0.f;
                mm4(w0p, h1s, 8 * 1 + jt, acc);
                const float bF = b0s[128 + j], wF = wxs[128 + j];
#pragma unroll
                for (int rt = 0; rt < 4; ++rt) {
                    f32x4 xv = *reinterpret_cast<const f32x4*>(&xs[rt * 16 + quad * 4]);
#pragma unroll
                    for (int r = 0; r < 4; ++r)
                        c1[q][rt][r] *= sigf(acc[rt][r] + bF + xv[r] * wF);
                }
            }
            // phase I (0) * G (2)
            {
                f32x4 aI[4], aG[4];
#pragma unroll
                for (int rt = 0; rt < 4; ++rt) { aI[rt] = 0.f; aG[rt] = 0.f; }
                mm4(w0p, h1s, 8 * 0 + jt, aI);
                mm4(w0p, h1s, 8 * 2 + jt, aG);
                const float bI = b0s[j], wI = wxs[j];
                const float bG = b0s[256 + j], wG = wxs[256 + j];
#pragma unroll
                for (int rt = 0; rt < 4; ++rt) {
                    f32x4 xv = *reinterpret_cast<const f32x4*>(&xs[rt * 16 + quad * 4]);
#pragma unroll
                    for (int r = 0; r < 4; ++r)
                        c1[q][rt][r] += sigf(aI[rt][r] + bI + xv[r] * wI) *
                                        tanhf_(aG[rt][r] + bG + xv[r] * wG);
                }
            }
            // phase O (3) -> h1
            {
                f32x4 acc[4];
#pragma unroll
                for (int rt = 0; rt < 4; ++rt) acc[rt] = 0.f;
                mm4(w0p, h1s, 8 * 3 + jt, acc);
                const float bO = b0s[384 + j], wO = wxs[384 + j];
#pragma unroll
                for (int rt = 0; rt < 4; ++rt) {
                    f32x4 xv = *reinterpret_cast<const f32x4*>(&xs[rt * 16 + quad * 4]);
#pragma unroll
                    for (int r = 0; r < 4; ++r)
                        h1v[q][rt][r] = sigf(acc[rt][r] + bO + xv[r] * wO) * tanhf_(c1[q][rt][r]);
                }
            }
        }
        __syncthreads();   // all waves done reading h1s
#pragma unroll
        for (int q = 0; q < 2; ++q) {
            const int j = (w + 4 * q) * 16 + col;
#pragma unroll
            for (int rt = 0; rt < 4; ++rt)
#pragma unroll
                for (int r = 0; r < 4; ++r)
                    h1s[rt * 16 + quad * 4 + r][j] = f2h_bits(h1v[q][rt][r]);
        }
        __syncthreads();   // new h1s visible

        // ---------------- layer 1: gates = h1_new @ Wih1^T + h2 @ Whh1^T + b1
#pragma unroll
        for (int q = 0; q < 2; ++q) {
            const int jt = w + 4 * q;
            const int j = jt * 16 + col;
            // F
            {
                f32x4 acc[4];
#pragma unroll
                for (int rt = 0; rt < 4; ++rt) acc[rt] = 0.f;
                mm4(w1ip, h1s, 8 + jt, acc);
                mm4(w1hp, h2s, 8 + jt, acc);
                const float bF = b1s[128 + j];
#pragma unroll
                for (int rt = 0; rt < 4; ++rt)
#pragma unroll
                    for (int r = 0; r < 4; ++r)
                        c2[q][rt][r] *= sigf(acc[rt][r] + bF);
            }
            // I * G
            {
                f32x4 aI[4], aG[4];
#pragma unroll
                for (int rt = 0; rt < 4; ++rt) { aI[rt] = 0.f; aG[rt] = 0.f; }
                mm4(w1ip, h1s, 0 + jt, aI);
                mm4(w1hp, h2s, 0 + jt, aI);
                mm4(w1ip, h1s, 16 + jt, aG);
                mm4(w1hp, h2s, 16 + jt, aG);
                const float bI = b1s[j], bG = b1s[256 + j];
#pragma unroll
                for (int rt = 0; rt < 4; ++rt)
#pragma unroll
                    for (int r = 0; r < 4; ++r)
                        c2[q][rt][r] += sigf(aI[rt][r] + bI) * tanhf_(aG[rt][r] + bG);
            }
            // O -> h2
            {
                f32x4 acc[4];
#pragma unroll
                for (int rt = 0; rt < 4; ++rt) acc[rt] = 0.f;
                mm4(w1ip, h1s, 24 + jt, acc);
                mm4(w1hp, h2s, 24 + jt, acc);
                const float bO = b1s[384 + j];
#pragma unroll
                for (int rt = 0; rt < 4; ++rt)
#pragma unroll
                    for (int r = 0; r < 4; ++r)
                        h2v[q][rt][r] = sigf(acc[rt][r] + bO) * tanhf_(c2[q][rt][r]);
            }
        }
        __syncthreads();   // all waves done reading h2s
#pragma unroll
        for (int q = 0; q < 2; ++q) {
            const int j = (w + 4 * q) * 16 + col;
#pragma unroll
            for (int rt = 0; rt < 4; ++rt)
#pragma unroll
                for (int r = 0; r < 4; ++r)
                    h2s[rt * 16 + quad * 4 + r][j] = f2h_bits(h2v[q][rt][r]);
        }
    }

    // final hidden state of layer 2 -> global (fp32), straight from registers
#pragma unroll
    for (int q = 0; q < 2; ++q) {
        const int j = (w + 4 * q) * 16 + col;
#pragma unroll
        for (int rt = 0; rt < 4; ++rt)
#pragma unroll
            for (int r = 0; r < 4; ++r) {
                int n = n0 + rt * 16 + quad * 4 + r;
                if (n < NN) h2out[(size_t)n * HH + j] = h2v[q][rt][r];
            }
    }
}

// ---------------------------------------------------------------------------
// GCN pieces (fp32)
// ---------------------------------------------------------------------------
__global__ void deg_init(float* __restrict__ deg) {
    int i = blockIdx.x * 256 + threadIdx.x;
    if (i < NN) deg[i] = 1.f;   // self loop
}
__global__ void deg_edges(const int* __restrict__ ei, float* __restrict__ deg) {
    int e = blockIdx.x * 256 + threadIdx.x;
    if (e < EE) unsafeAtomicAdd(&deg[ei[EE + e]], 1.f);   // col = target
}
__global__ void dinv_k(const float* __restrict__ deg, float* __restrict__ dinv) {
    int i = blockIdx.x * 256 + threadIdx.x;
    if (i < NN) dinv[i] = rsqrtf(fmaxf(deg[i], 1.f));
}

// exclusive scan of per-node in-edge counts (deg-1) -> off[0..NN]
__global__ void scan_off(const float* __restrict__ deg, int* __restrict__ off) {
    __shared__ int sp[256];
    const int tid = threadIdx.x;
    const int chunk = (NN + 255) / 256;   // 196
    const int i0 = tid * chunk;
    int s = 0;
    for (int i = 0; i < chunk; ++i) {
        int idx = i0 + i;
        if (idx < NN) s += (int)deg[idx] - 1;
    }
    sp[tid] = s;
    __syncthreads();
    for (int o = 1; o < 256; o <<= 1) {
        int v = (tid >= o) ? sp[tid - o] : 0;
        __syncthreads();
        sp[tid] += v;
        __syncthreads();
    }
    int run = sp[tid] - s;   // exclusive base
    for (int i = 0; i < chunk; ++i) {
        int idx = i0 + i;
        if (idx < NN) { off[idx] = run; run += (int)deg[idx] - 1; }
    }
    if (tid == 255) off[NN] = sp[255];
}

// fill CSR: for each edge, place (row, enorm) into target bucket
__global__ void csr_fill(const int* __restrict__ ei, const float* __restrict__ dinv,
                         const int* __restrict__ off, int* __restrict__ cur,
                         int* __restrict__ crow, float* __restrict__ cw) {
    int e = blockIdx.x * 256 + threadIdx.x;
    if (e >= EE) return;
    int r = ei[e], c = ei[EE + e];
    int p = atomicAdd(&cur[c], 1);
    int idx = off[c] + p;
    crow[idx] = r;
    cw[idx] = dinv[r] * dinv[c];
}

// hw = h @ Wg   ([N,128] x [128,128]); 32 nodes per block
__global__ void gcn_gemm(const float* __restrict__ h, const float* __restrict__ Wg,
                         float* __restrict__ hw) {
    __shared__ float hsT[128][36];
    int tid = threadIdx.x;
    int n0 = blockIdx.x * 32;
#pragma unroll
    for (int c = 0; c < 16; ++c) {
        int lin = c * 256 + tid;
        int m = lin >> 7, k = lin & 127;
        int n = n0 + m;
        hsT[k][m] = (n < NN) ? h[(size_t)n * HH + k] : 0.f;
    }
    __syncthreads();
    int j = tid & 127, p = tid >> 7;
    float acc[16];
#pragma unroll
    for (int m = 0; m < 16; ++m) acc[m] = 0.f;
    for (int k = 0; k < 128; ++k) {
        float wg = Wg[k * 128 + j];
        const float4* hp = reinterpret_cast<const float4*>(&hsT[k][p * 16]);
        float4 a = hp[0], b = hp[1], c = hp[2], d = hp[3];
        acc[0]  += a.x * wg; acc[1]  += a.y * wg; acc[2]  += a.z * wg; acc[3]  += a.w * wg;
        acc[4]  += b.x * wg; acc[5]  += b.y * wg; acc[6]  += b.z * wg; acc[7]  += b.w * wg;
        acc[8]  += c.x * wg; acc[9]  += c.y * wg; acc[10] += c.z * wg; acc[11] += c.w * wg;
        acc[12] += d.x * wg; acc[13] += d.y * wg; acc[14] += d.z * wg; acc[15] += d.w * wg;
    }
#pragma unroll
    for (int m = 0; m < 16; ++m) {
        int n = n0 + p * 16 + m;
        if (n < NN) hw[(size_t)n * HH + j] = acc[m];
    }
}

// Fused: aggregate (self-loop + CSR gather) + bias + LayerNorm + ReLU + residual.
// 2 nodes per block, 128 threads (2 waves) per node, no atomics.
__global__ __launch_bounds__(256) void gcn_agg(
    const float* __restrict__ hw, const int* __restrict__ off,
    const int* __restrict__ crow, const float* __restrict__ cw,
    const float* __restrict__ dinv, const float* __restrict__ bg,
    const float* __restrict__ gamma, const float* __restrict__ beta,
    float* __restrict__ h) {
    __shared__ float xch[4][2];
    const int tid = threadIdx.x;
    const int half = tid >> 7;
    const int f = tid & 127;
    const int v = blockIdx.x * 2 + half;     // NN even -> always < NN
    const float d = dinv[v];
    float acc = bg[f] + d * d * hw[v * HH + f];
    const int s1 = off[v + 1];
    for (int s = off[v]; s < s1; ++s) {
        int r = crow[s];
        float wv = cw[s];
        acc = fmaf(wv, hw[r * HH + f], acc);
    }
    // LayerNorm over 128 features (2 waves)
    float sum = acc, sq = acc * acc;
#pragma unroll
    for (int o = 32; o; o >>= 1) { sum += __shfl_xor(sum, o); sq += __shfl_xor(sq, o); }
    int wid = tid >> 6;
    if ((tid & 63) == 0) { xch[wid][0] = sum; xch[wid][1] = sq; }
    __syncthreads();
    sum += xch[wid ^ 1][0]; sq += xch[wid ^ 1][1];
    float mu = sum * (1.f / 128.f);
    float var = sq * (1.f / 128.f) - mu * mu;
    float rn = rsqrtf(var + 1e-5f);
    float o = (acc - mu) * rn * gamma[f] + beta[f];
    h[v * HH + f] = fmaxf(o, 0.f) + h[v * HH + f];
}

__global__ void pool_k(const float* __restrict__ h, float* __restrict__ pooled) {
    int j = threadIdx.x & 127, p = threadIdx.x >> 7;
    float s = 0.f;
    for (int n = blockIdx.x * 2 + p; n < NN; n += 512) s += h[(size_t)n * HH + j];
    unsafeAtomicAdd(&pooled[j], s);
}

__global__ void final_k(const float* __restrict__ pooled, const float* __restrict__ Wout,
                        const float* __restrict__ bout, float* __restrict__ out) {
    int lane = threadIdx.x;
    float s = pooled[lane] * Wout[lane] + pooled[lane + 64] * Wout[lane + 64];
#pragma unroll
    for (int o = 32; o; o >>= 1) s += __shfl_xor(s, o);
    if (lane == 0) out[0] = s * (1.f / (float)NN) + bout[0];
}

// ---------------------------------------------------------------------------
extern "C" void kernel_launch(void* const* d_in, const int* in_sizes, int n_in,
                              void* d_out, int out_size, void* d_ws, size_t ws_size,
                              hipStream_t stream) {
    const float* lc   = (const float*)d_in[0];
    const int*   ei   = (const int*)d_in[1];
    const float* Wih0 = (const float*)d_in[2];
    const float* Whh0 = (const float*)d_in[3];
    const float* bih0 = (const float*)d_in[4];
    const float* bhh0 = (const float*)d_in[5];
    const float* Wih1 = (const float*)d_in[6];
    const float* Whh1 = (const float*)d_in[7];
    const float* bih1 = (const float*)d_in[8];
    const float* bhh1 = (const float*)d_in[9];
    const float* Wout = (const float*)d_in[22];
    const float* bout = (const float*)d_in[23];
    float* out = (float*)d_out;

    // workspace layout (float units), ~67 MB total:
    //  h  [0, 6.4e6) | hw [6.4e6, 12.8e6) | CSR [12.8e6, ~16.1e6) | P [16.4e6, ...)
    //  xT aliases [6.4e6, 16.4e6): live only between transpose and lstm;
    //  CSR is built after lstm (xT dead), does not overlap h/hw.
    float* ws   = (float*)d_ws;
    float* h    = ws;
    float* hw   = ws + 6400000;
    float* xT   = ws + 6400000;                    // spans 10e6 floats
    int*   off  = (int*)(ws + 12800000);           // NN+1 (pad to 50048)
    int*   cur  = off + 50048;                     // NN (pad to 50048)
    int*   crow = cur + 50048;                     // EE
    float* cw   = (float*)(crow + EE);             // EE
    float* P      = ws + 16400064;
    float* deg    = P;                             // NN
    float* dinv   = deg + 50000;                   // NN
    float* b0g    = dinv + 50000;                  // 512
    float* b1g    = b0g + 512;
    float* wxg    = b1g + 512;
    float* pooled = wxg + 512;                     // 128
    unsigned short* w0p  = (unsigned short*)(pooled + 128);
    unsigned short* w1ip = w0p + 65536;
    unsigned short* w1hp = w1ip + 65536;

    pack_w<<<128, 64, 0, stream>>>(Whh0, w0p);
    pack_w<<<128, 64, 0, stream>>>(Wih1, w1ip);
    pack_w<<<128, 64, 0, stream>>>(Whh1, w1hp);
    bias_prep<<<2, 256, 0, stream>>>(bih0, bhh0, bih1, bhh1, Wih0, b0g, b1g, wxg);
    {
        dim3 g((TT + 31) / 32, (NN + 31) / 32), b(32, 8);
        transpose_lc<<<g, b, 0, stream>>>(lc, xT);
    }
    deg_init<<<(NN + 255) / 256, 256, 0, stream>>>(deg);
    deg_edges<<<(EE + 255) / 256, 256, 0, stream>>>(ei, deg);
    dinv_k<<<(NN + 255) / 256, 256, 0, stream>>>(deg, dinv);

    lstm_kernel<<<(NN + 63) / 64, 256, 0, stream>>>(xT, w0p, w1ip, w1hp, b0g, b1g, wxg, h);

    // CSR build (xT region dead now)
    hipMemsetAsync(cur, 0, 50000 * sizeof(int), stream);
    scan_off<<<1, 256, 0, stream>>>(deg, off);
    csr_fill<<<(EE + 255) / 256, 256, 0, stream>>>(ei, dinv, off, cur, crow, cw);

    for (int l = 0; l < 3; ++l) {
        const float* Wg = (const float*)d_in[10 + 4 * l];
        const float* bg = (const float*)d_in[11 + 4 * l];
        const float* gm = (const float*)d_in[12 + 4 * l];
        const float* bt = (const float*)d_in[13 + 4 * l];
        gcn_gemm<<<(NN + 31) / 32, 256, 0, stream>>>(h, Wg, hw);
        gcn_agg<<<NN / 2, 256, 0, stream>>>(hw, off, crow, cw, dinv, bg, gm, bt, h);
    }

    hipMemsetAsync(pooled, 0, HH * sizeof(float), stream);
    pool_k<<<256, 256, 0, stream>>>(h, pooled);
    final_k<<<1, 64, 0, stream>>>(pooled, Wout, bout, out);
}

// Round 3
// 14953.346 us; speedup vs baseline: 2.2276x; 2.2276x over previous
//
#include <hip/hip_runtime.h>

// Problem constants (fixed by the reference)
#define NN 50000
#define TT 200
#define HH 128
#define EE 1600000

typedef _Float16 f16x8 __attribute__((ext_vector_type(8)));
typedef float f32x4 __attribute__((ext_vector_type(4)));

__device__ __forceinline__ float sigf(float x) {
    return __builtin_amdgcn_rcpf(1.f + __expf(-x));
}
__device__ __forceinline__ float tanhf_(float x) {
    return 1.f - 2.f * __builtin_amdgcn_rcpf(__expf(2.f * x) + 1.f);
}
__device__ __forceinline__ f32x4 sig4(f32x4 x) {
    f32x4 r; r[0] = sigf(x[0]); r[1] = sigf(x[1]); r[2] = sigf(x[2]); r[3] = sigf(x[3]); return r;
}
__device__ __forceinline__ f32x4 tanh4(f32x4 x) {
    f32x4 r; r[0] = tanhf_(x[0]); r[1] = tanhf_(x[1]); r[2] = tanhf_(x[2]); r[3] = tanhf_(x[3]); return r;
}
__device__ __forceinline__ f32x4 splat4(float s) { f32x4 r = {s, s, s, s}; return r; }
__device__ __forceinline__ unsigned short f2h_bits(float x) {
    _Float16 h = (_Float16)x;
    union { _Float16 h; unsigned short u; } cv; cv.h = h; return cv.u;
}
__device__ __forceinline__ float h2f_bits(unsigned short u) {
    union { _Float16 h; unsigned short u; } cv; cv.u = u; return (float)cv.h;
}

// ---------------------------------------------------------------------------
// Weight packing: W is (512,128) row-major (PyTorch [4H, H]).
// MFMA-16x16x32 B-fragment order: tile jn (0..31 over gate-cols), chunk kk (0..3):
// out[(jn*4+kk)*512 + L*8 + i] = W[jn*16 + (L&15)][kk*32 + (L>>4)*8 + i]  (f16)
// ---------------------------------------------------------------------------
__global__ void pack_w(const float* __restrict__ W, unsigned short* __restrict__ out) {
    int tile = blockIdx.x;          // jn*4 + kk
    int jn = tile >> 2, kk = tile & 3;
    int L = threadIdx.x;            // 0..63
    int n = jn * 16 + (L & 15);
    int k0 = kk * 32 + (L >> 4) * 8;
    unsigned short* dst = out + (size_t)tile * 512 + L * 8;
#pragma unroll
    for (int i = 0; i < 8; ++i) dst[i] = f2h_bits(W[n * 128 + k0 + i]);
}

__global__ void bias_prep(const float* __restrict__ bih0, const float* __restrict__ bhh0,
                          const float* __restrict__ bih1, const float* __restrict__ bhh1,
                          const float* __restrict__ wih0,
                          float* __restrict__ b0g, float* __restrict__ b1g, float* __restrict__ wxg) {
    int i = blockIdx.x * 256 + threadIdx.x;
    if (i < 512) {
        b0g[i] = bih0[i] + bhh0[i];
        b1g[i] = bih1[i] + bhh1[i];
        wxg[i] = wih0[i];
    }
}

// lightcurve [N][T] -> xT [T][N]
__global__ void transpose_lc(const float* __restrict__ lc, float* __restrict__ xT) {
    __shared__ float tile[32][33];
    int tx = threadIdx.x, ty = threadIdx.y;    // 32 x 8
    int n0 = blockIdx.y * 32, t0 = blockIdx.x * 32;
#pragma unroll
    for (int i = 0; i < 32; i += 8) {
        int n = n0 + ty + i, t = t0 + tx;
        if (n < NN && t < TT) tile[ty + i][tx] = lc[(size_t)n * TT + t];
    }
    __syncthreads();
#pragma unroll
    for (int i = 0; i < 32; i += 8) {
        int t = t0 + ty + i, n = n0 + tx;
        if (n < NN && t < TT) xT[(size_t)t * NN + n] = tile[tx][ty + i];
    }
}

// ---------------------------------------------------------------------------
// Fused 2-layer LSTM. Block = 256 threads (4 waves), 64 nodes, 200 steps.
// ALL state in individually NAMED registers (no private arrays -> no scratch).
// Wave w owns cols j = {w*16+col, (w+4)*16+col}. All 4 gates accumulated
// together per col-group (64 acc VGPRs transient). h in LDS f16, c in VGPRs.
// ---------------------------------------------------------------------------

// A-fragment load from LDS h-buffer
#define LDA(HS, RT, KK) \
    (*reinterpret_cast<const f16x8*>(&HS[(RT) * 16 + col][(KK) * 32 + quad * 8]))

#define MFMA16(A, B, C) __builtin_amdgcn_mfma_f32_16x16x32_f16((A), (B), (C), 0, 0, 0)

// One K-chunk (32 wide): 4 B-frags (one per gate), 4 A-frags (row tiles), 16 MFMAs
#define MMCHUNK(HS, PI, PF, PG, PO, KK)                                         \
    {                                                                           \
        f16x8 bI_ = *reinterpret_cast<const f16x8*>((PI) + (KK) * 512);         \
        f16x8 bF_ = *reinterpret_cast<const f16x8*>((PF) + (KK) * 512);         \
        f16x8 bG_ = *reinterpret_cast<const f16x8*>((PG) + (KK) * 512);         \
        f16x8 bO_ = *reinterpret_cast<const f16x8*>((PO) + (KK) * 512);         \
        f16x8 a0_ = LDA(HS, 0, KK);                                             \
        f16x8 a1_ = LDA(HS, 1, KK);                                             \
        f16x8 a2_ = LDA(HS, 2, KK);                                             \
        f16x8 a3_ = LDA(HS, 3, KK);                                             \
        aI0 = MFMA16(a0_, bI_, aI0); aI1 = MFMA16(a1_, bI_, aI1);               \
        aI2 = MFMA16(a2_, bI_, aI2); aI3 = MFMA16(a3_, bI_, aI3);               \
        aF0 = MFMA16(a0_, bF_, aF0); aF1 = MFMA16(a1_, bF_, aF1);               \
        aF2 = MFMA16(a2_, bF_, aF2); aF3 = MFMA16(a3_, bF_, aF3);               \
        aG0 = MFMA16(a0_, bG_, aG0); aG1 = MFMA16(a1_, bG_, aG1);               \
        aG2 = MFMA16(a2_, bG_, aG2); aG3 = MFMA16(a3_, bG_, aG3);               \
        aO0 = MFMA16(a0_, bO_, aO0); aO1 = MFMA16(a1_, bO_, aO1);               \
        aO2 = MFMA16(a2_, bO_, aO2); aO3 = MFMA16(a3_, bO_, aO3);               \
    }

// Layer-0 activation for one row-tile (with x*w_ih terms)
#define ACT0(RT, C, H, AI, AF, AG, AO)                                          \
    {                                                                           \
        f32x4 xv_ = *reinterpret_cast<const f32x4*>(&xs[(RT) * 16 + quad * 4]); \
        f32x4 gi_ = AI + splat4(bIs) + xv_ * splat4(wIs);                       \
        f32x4 gf_ = AF + splat4(bFs) + xv_ * splat4(wFs);                       \
        f32x4 gg_ = AG + splat4(bGs) + xv_ * splat4(wGs);                       \
        f32x4 go_ = AO + splat4(bOs) + xv_ * splat4(wOs);                       \
        C = sig4(gf_) * C + sig4(gi_) * tanh4(gg_);                             \
        H = sig4(go_) * tanh4(C);                                               \
    }

// Layer-1 activation (no x terms)
#define ACT1(C, H, AI, AF, AG, AO)                                              \
    {                                                                           \
        f32x4 gi_ = AI + splat4(bIs);                                           \
        f32x4 gf_ = AF + splat4(bFs);                                           \
        f32x4 gg_ = AG + splat4(bGs);                                           \
        f32x4 go_ = AO + splat4(bOs);                                           \
        C = sig4(gf_) * C + sig4(gi_) * tanh4(gg_);                             \
        H = sig4(go_) * tanh4(C);                                               \
    }

// Full layer-0 pass for one col-group Q
#define L0Q(Q, C0, C1, C2, C3, H0, H1, H2, H3)                                  \
    {                                                                           \
        const int jt_ = w + 4 * (Q);                                            \
        const int j_ = jt_ * 16 + col;                                          \
        const unsigned short* pI_ = w0p + (size_t)jt_ * 2048 + lane * 8;        \
        const unsigned short* pF_ = w0p + (size_t)(8 + jt_) * 2048 + lane * 8;  \
        const unsigned short* pG_ = w0p + (size_t)(16 + jt_) * 2048 + lane * 8; \
        const unsigned short* pO_ = w0p + (size_t)(24 + jt_) * 2048 + lane * 8; \
        f32x4 aI0 = {}, aI1 = {}, aI2 = {}, aI3 = {};                           \
        f32x4 aF0 = {}, aF1 = {}, aF2 = {}, aF3 = {};                           \
        f32x4 aG0 = {}, aG1 = {}, aG2 = {}, aG3 = {};                           \
        f32x4 aO0 = {}, aO1 = {}, aO2 = {}, aO3 = {};                           \
        MMCHUNK(h1s, pI_, pF_, pG_, pO_, 0)                                     \
        MMCHUNK(h1s, pI_, pF_, pG_, pO_, 1)                                     \
        MMCHUNK(h1s, pI_, pF_, pG_, pO_, 2)                                     \
        MMCHUNK(h1s, pI_, pF_, pG_, pO_, 3)                                     \
        const float bIs = b0s[j_], bFs = b0s[128 + j_];                         \
        const float bGs = b0s[256 + j_], bOs = b0s[384 + j_];                   \
        const float wIs = wxs[j_], wFs = wxs[128 + j_];                         \
        const float wGs = wxs[256 + j_], wOs = wxs[384 + j_];                   \
        ACT0(0, C0, H0, aI0, aF0, aG0, aO0)                                     \
        ACT0(1, C1, H1, aI1, aF1, aG1, aO1)                                     \
        ACT0(2, C2, H2, aI2, aF2, aG2, aO2)                                     \
        ACT0(3, C3, H3, aI3, aF3, aG3, aO3)                                     \
    }

// Full layer-1 pass for one col-group Q (K=256: h1s@w1ip then h2s@w1hp)
#define L1Q(Q, C0, C1, C2, C3, H0, H1, H2, H3)                                  \
    {                                                                           \
        const int jt_ = w + 4 * (Q);                                            \
        const int j_ = jt_ * 16 + col;                                          \
        const unsigned short* uI_ = w1ip + (size_t)jt_ * 2048 + lane * 8;       \
        const unsigned short* uF_ = w1ip + (size_t)(8 + jt_) * 2048 + lane * 8; \
        const unsigned short* uG_ = w1ip + (size_t)(16 + jt_) * 2048 + lane * 8;\
        const unsigned short* uO_ = w1ip + (size_t)(24 + jt_) * 2048 + lane * 8;\
        const unsigned short* vI_ = w1hp + (size_t)jt_ * 2048 + lane * 8;       \
        const unsigned short* vF_ = w1hp + (size_t)(8 + jt_) * 2048 + lane * 8; \
        const unsigned short* vG_ = w1hp + (size_t)(16 + jt_) * 2048 + lane * 8;\
        const unsigned short* vO_ = w1hp + (size_t)(24 + jt_) * 2048 + lane * 8;\
        f32x4 aI0 = {}, aI1 = {}, aI2 = {}, aI3 = {};                           \
        f32x4 aF0 = {}, aF1 = {}, aF2 = {}, aF3 = {};                           \
        f32x4 aG0 = {}, aG1 = {}, aG2 = {}, aG3 = {};                           \
        f32x4 aO0 = {}, aO1 = {}, aO2 = {}, aO3 = {};                           \
        MMCHUNK(h1s, uI_, uF_, uG_, uO_, 0)                                     \
        MMCHUNK(h1s, uI_, uF_, uG_, uO_, 1)                                     \
        MMCHUNK(h1s, uI_, uF_, uG_, uO_, 2)                                     \
        MMCHUNK(h1s, uI_, uF_, uG_, uO_, 3)                                     \
        MMCHUNK(h2s, vI_, vF_, vG_, vO_, 0)                                     \
        MMCHUNK(h2s, vI_, vF_, vG_, vO_, 1)                                     \
        MMCHUNK(h2s, vI_, vF_, vG_, vO_, 2)                                     \
        MMCHUNK(h2s, vI_, vF_, vG_, vO_, 3)                                     \
        const float bIs = b1s[j_], bFs = b1s[128 + j_];                         \
        const float bGs = b1s[256 + j_], bOs = b1s[384 + j_];                   \
        ACT1(C0, H0, aI0, aF0, aG0, aO0)                                        \
        ACT1(C1, H1, aI1, aF1, aG1, aO1)                                        \
        ACT1(C2, H2, aI2, aF2, aG2, aO2)                                        \
        ACT1(C3, H3, aI3, aF3, aG3, aO3)                                        \
    }

// Write one col-group's h values (f16) into LDS h-buffer
#define WRH1(HS, RT, Q, H)                                                      \
    HS[(RT) * 16 + quad * 4 + 0][(w + 4 * (Q)) * 16 + col] = f2h_bits(H[0]);    \
    HS[(RT) * 16 + quad * 4 + 1][(w + 4 * (Q)) * 16 + col] = f2h_bits(H[1]);    \
    HS[(RT) * 16 + quad * 4 + 2][(w + 4 * (Q)) * 16 + col] = f2h_bits(H[2]);    \
    HS[(RT) * 16 + quad * 4 + 3][(w + 4 * (Q)) * 16 + col] = f2h_bits(H[3]);

#define WRHQ(HS, Q, H0, H1, H2, H3)                                             \
    WRH1(HS, 0, Q, H0) WRH1(HS, 1, Q, H1) WRH1(HS, 2, Q, H2) WRH1(HS, 3, Q, H3)

__global__ __launch_bounds__(256, 2) void lstm_kernel(
    const float* __restrict__ xT,
    const unsigned short* __restrict__ w0p,
    const unsigned short* __restrict__ w1ip,
    const unsigned short* __restrict__ w1hp,
    const float* __restrict__ b0g, const float* __restrict__ b1g,
    const float* __restrict__ wxg,
    float* __restrict__ h2out) {
    __shared__ unsigned short h1s[64][136];
    __shared__ unsigned short h2s[64][136];
    __shared__ float xs[64];
    __shared__ float b0s[512], b1s[512], wxs[512];

    const int tid = threadIdx.x;
    const int w = tid >> 6;
    const int lane = tid & 63;
    const int col = lane & 15;
    const int quad = lane >> 4;
    const int n0 = blockIdx.x * 64;

    for (int i = tid; i < 64 * 136; i += 256) { (&h1s[0][0])[i] = 0; (&h2s[0][0])[i] = 0; }
    for (int i = tid; i < 512; i += 256) { b0s[i] = b0g[i]; b1s[i] = b1g[i]; wxs[i] = wxg[i]; }

    // persistent cell states: c{layer}_{q}_{rowtile}, 4 rows each (f32x4)
    f32x4 c1_0_0 = {}, c1_0_1 = {}, c1_0_2 = {}, c1_0_3 = {};
    f32x4 c1_1_0 = {}, c1_1_1 = {}, c1_1_2 = {}, c1_1_3 = {};
    f32x4 c2_0_0 = {}, c2_0_1 = {}, c2_0_2 = {}, c2_0_3 = {};
    f32x4 c2_1_0 = {}, c2_1_1 = {}, c2_1_2 = {}, c2_1_3 = {};

#pragma unroll 1
    for (int t = 0; t < TT; ++t) {
        if (tid < 64) {
            int n = n0 + tid;
            xs[tid] = (n < NN) ? xT[(size_t)t * NN + n] : 0.f;
        }
        __syncthreads();   // xs + previous-step h2s writes visible

        // layer 0: transient h1 values (named, freed after LDS write)
        {
            f32x4 h1_0_0, h1_0_1, h1_0_2, h1_0_3;
            f32x4 h1_1_0, h1_1_1, h1_1_2, h1_1_3;
            L0Q(0, c1_0_0, c1_0_1, c1_0_2, c1_0_3, h1_0_0, h1_0_1, h1_0_2, h1_0_3)
            L0Q(1, c1_1_0, c1_1_1, c1_1_2, c1_1_3, h1_1_0, h1_1_1, h1_1_2, h1_1_3)
            __syncthreads();   // all waves done reading old h1s
            WRHQ(h1s, 0, h1_0_0, h1_0_1, h1_0_2, h1_0_3)
            WRHQ(h1s, 1, h1_1_0, h1_1_1, h1_1_2, h1_1_3)
        }
        __syncthreads();   // new h1s visible

        // layer 1
        {
            f32x4 h2_0_0, h2_0_1, h2_0_2, h2_0_3;
            f32x4 h2_1_0, h2_1_1, h2_1_2, h2_1_3;
            L1Q(0, c2_0_0, c2_0_1, c2_0_2, c2_0_3, h2_0_0, h2_0_1, h2_0_2, h2_0_3)
            L1Q(1, c2_1_0, c2_1_1, c2_1_2, c2_1_3, h2_1_0, h2_1_1, h2_1_2, h2_1_3)
            __syncthreads();   // all waves done reading old h2s
            WRHQ(h2s, 0, h2_0_0, h2_0_1, h2_0_2, h2_0_3)
            WRHQ(h2s, 1, h2_1_0, h2_1_1, h2_1_2, h2_1_3)
        }
    }

    // final h2 -> global (each thread reads back exactly the cells it wrote)
#pragma unroll
    for (int q = 0; q < 2; ++q) {
        const int j = (w + 4 * q) * 16 + col;
#pragma unroll
        for (int rt = 0; rt < 4; ++rt)
#pragma unroll
            for (int r = 0; r < 4; ++r) {
                int m = rt * 16 + quad * 4 + r;
                int n = n0 + m;
                if (n < NN) h2out[(size_t)n * HH + j] = h2f_bits(h2s[m][j]);
            }
    }
}

// ---------------------------------------------------------------------------
// GCN pieces (fp32)
// ---------------------------------------------------------------------------
__global__ void deg_init(float* __restrict__ deg) {
    int i = blockIdx.x * 256 + threadIdx.x;
    if (i < NN) deg[i] = 1.f;   // self loop
}
__global__ void deg_edges(const int* __restrict__ ei, float* __restrict__ deg) {
    int e = blockIdx.x * 256 + threadIdx.x;
    if (e < EE) unsafeAtomicAdd(&deg[ei[EE + e]], 1.f);   // col = target
}
__global__ void dinv_k(const float* __restrict__ deg, float* __restrict__ dinv) {
    int i = blockIdx.x * 256 + threadIdx.x;
    if (i < NN) dinv[i] = rsqrtf(fmaxf(deg[i], 1.f));
}

// exclusive scan of per-node in-edge counts (deg-1) -> off[0..NN]
__global__ void scan_off(const float* __restrict__ deg, int* __restrict__ off) {
    __shared__ int sp[256];
    const int tid = threadIdx.x;
    const int chunk = (NN + 255) / 256;
    const int i0 = tid * chunk;
    int s = 0;
    for (int i = 0; i < chunk; ++i) {
        int idx = i0 + i;
        if (idx < NN) s += (int)deg[idx] - 1;
    }
    sp[tid] = s;
    __syncthreads();
    for (int o = 1; o < 256; o <<= 1) {
        int v = (tid >= o) ? sp[tid - o] : 0;
        __syncthreads();
        sp[tid] += v;
        __syncthreads();
    }
    int run = sp[tid] - s;
    for (int i = 0; i < chunk; ++i) {
        int idx = i0 + i;
        if (idx < NN) { off[idx] = run; run += (int)deg[idx] - 1; }
    }
    if (tid == 255) off[NN] = sp[255];
}

__global__ void csr_fill(const int* __restrict__ ei, const float* __restrict__ dinv,
                         const int* __restrict__ off, int* __restrict__ cur,
                         int* __restrict__ crow, float* __restrict__ cw) {
    int e = blockIdx.x * 256 + threadIdx.x;
    if (e >= EE) return;
    int r = ei[e], c = ei[EE + e];
    int p = atomicAdd(&cur[c], 1);
    int idx = off[c] + p;
    crow[idx] = r;
    cw[idx] = dinv[r] * dinv[c];
}

// hw = h @ Wg   ([N,128] x [128,128]); 32 nodes per block
__global__ void gcn_gemm(const float* __restrict__ h, const float* __restrict__ Wg,
                         float* __restrict__ hw) {
    __shared__ float hsT[128][36];
    int tid = threadIdx.x;
    int n0 = blockIdx.x * 32;
#pragma unroll
    for (int c = 0; c < 16; ++c) {
        int lin = c * 256 + tid;
        int m = lin >> 7, k = lin & 127;
        int n = n0 + m;
        hsT[k][m] = (n < NN) ? h[(size_t)n * HH + k] : 0.f;
    }
    __syncthreads();
    int j = tid & 127, p = tid >> 7;
    float acc[16];
#pragma unroll
    for (int m = 0; m < 16; ++m) acc[m] = 0.f;
    for (int k = 0; k < 128; ++k) {
        float wg = Wg[k * 128 + j];
        const float4* hp = reinterpret_cast<const float4*>(&hsT[k][p * 16]);
        float4 a = hp[0], b = hp[1], c = hp[2], d = hp[3];
        acc[0]  += a.x * wg; acc[1]  += a.y * wg; acc[2]  += a.z * wg; acc[3]  += a.w * wg;
        acc[4]  += b.x * wg; acc[5]  += b.y * wg; acc[6]  += b.z * wg; acc[7]  += b.w * wg;
        acc[8]  += c.x * wg; acc[9]  += c.y * wg; acc[10] += c.z * wg; acc[11] += c.w * wg;
        acc[12] += d.x * wg; acc[13] += d.y * wg; acc[14] += d.z * wg; acc[15] += d.w * wg;
    }
#pragma unroll
    for (int m = 0; m < 16; ++m) {
        int n = n0 + p * 16 + m;
        if (n < NN) hw[(size_t)n * HH + j] = acc[m];
    }
}

// Fused: self-loop + CSR gather + bias + LayerNorm + ReLU + residual
__global__ __launch_bounds__(256) void gcn_agg(
    const float* __restrict__ hw, const int* __restrict__ off,
    const int* __restrict__ crow, const float* __restrict__ cw,
    const float* __restrict__ dinv, const float* __restrict__ bg,
    const float* __restrict__ gamma, const float* __restrict__ beta,
    float* __restrict__ h) {
    __shared__ float xch[4][2];
    const int tid = threadIdx.x;
    const int half = tid >> 7;
    const int f = tid & 127;
    const int v = blockIdx.x * 2 + half;
    const float d = dinv[v];
    float acc = bg[f] + d * d * hw[v * HH + f];
    const int s1 = off[v + 1];
    for (int s = off[v]; s < s1; ++s) {
        int r = crow[s];
        float wv = cw[s];
        acc = fmaf(wv, hw[r * HH + f], acc);
    }
    float sum = acc, sq = acc * acc;
#pragma unroll
    for (int o = 32; o; o >>= 1) { sum += __shfl_xor(sum, o); sq += __shfl_xor(sq, o); }
    int wid = tid >> 6;
    if ((tid & 63) == 0) { xch[wid][0] = sum; xch[wid][1] = sq; }
    __syncthreads();
    sum += xch[wid ^ 1][0]; sq += xch[wid ^ 1][1];
    float mu = sum * (1.f / 128.f);
    float var = sq * (1.f / 128.f) - mu * mu;
    float rn = rsqrtf(var + 1e-5f);
    float o = (acc - mu) * rn * gamma[f] + beta[f];
    h[v * HH + f] = fmaxf(o, 0.f) + h[v * HH + f];
}

__global__ void pool_k(const float* __restrict__ h, float* __restrict__ pooled) {
    int j = threadIdx.x & 127, p = threadIdx.x >> 7;
    float s = 0.f;
    for (int n = blockIdx.x * 2 + p; n < NN; n += 512) s += h[(size_t)n * HH + j];
    unsafeAtomicAdd(&pooled[j], s);
}

__global__ void final_k(const float* __restrict__ pooled, const float* __restrict__ Wout,
                        const float* __restrict__ bout, float* __restrict__ out) {
    int lane = threadIdx.x;
    float s = pooled[lane] * Wout[lane] + pooled[lane + 64] * Wout[lane + 64];
#pragma unroll
    for (int o = 32; o; o >>= 1) s += __shfl_xor(s, o);
    if (lane == 0) out[0] = s * (1.f / (float)NN) + bout[0];
}

// ---------------------------------------------------------------------------
extern "C" void kernel_launch(void* const* d_in, const int* in_sizes, int n_in,
                              void* d_out, int out_size, void* d_ws, size_t ws_size,
                              hipStream_t stream) {
    const float* lc   = (const float*)d_in[0];
    const int*   ei   = (const int*)d_in[1];
    const float* Wih0 = (const float*)d_in[2];
    const float* Whh0 = (const float*)d_in[3];
    const float* bih0 = (const float*)d_in[4];
    const float* bhh0 = (const float*)d_in[5];
    const float* Wih1 = (const float*)d_in[6];
    const float* Whh1 = (const float*)d_in[7];
    const float* bih1 = (const float*)d_in[8];
    const float* bhh1 = (const float*)d_in[9];
    const float* Wout = (const float*)d_in[22];
    const float* bout = (const float*)d_in[23];
    float* out = (float*)d_out;

    float* ws   = (float*)d_ws;
    float* h    = ws;
    float* hw   = ws + 6400000;
    float* xT   = ws + 6400000;                    // aliases hw+CSR region pre-LSTM
    int*   off  = (int*)(ws + 12800000);
    int*   cur  = off + 50048;
    int*   crow = cur + 50048;
    float* cw   = (float*)(crow + EE);
    float* P      = ws + 16400064;
    float* deg    = P;
    float* dinv   = deg + 50000;
    float* b0g    = dinv + 50000;
    float* b1g    = b0g + 512;
    float* wxg    = b1g + 512;
    float* pooled = wxg + 512;
    unsigned short* w0p  = (unsigned short*)(pooled + 128);
    unsigned short* w1ip = w0p + 65536;
    unsigned short* w1hp = w1ip + 65536;

    pack_w<<<128, 64, 0, stream>>>(Whh0, w0p);
    pack_w<<<128, 64, 0, stream>>>(Wih1, w1ip);
    pack_w<<<128, 64, 0, stream>>>(Whh1, w1hp);
    bias_prep<<<2, 256, 0, stream>>>(bih0, bhh0, bih1, bhh1, Wih0, b0g, b1g, wxg);
    {
        dim3 g((TT + 31) / 32, (NN + 31) / 32), b(32, 8);
        transpose_lc<<<g, b, 0, stream>>>(lc, xT);
    }
    deg_init<<<(NN + 255) / 256, 256, 0, stream>>>(deg);
    deg_edges<<<(EE + 255) / 256, 256, 0, stream>>>(ei, deg);
    dinv_k<<<(NN + 255) / 256, 256, 0, stream>>>(deg, dinv);

    lstm_kernel<<<(NN + 63) / 64, 256, 0, stream>>>(xT, w0p, w1ip, w1hp, b0g, b1g, wxg, h);

    hipMemsetAsync(cur, 0, 50000 * sizeof(int), stream);
    scan_off<<<1, 256, 0, stream>>>(deg, off);
    csr_fill<<<(EE + 255) / 256, 256, 0, stream>>>(ei, dinv, off, cur, crow, cw);

    for (int l = 0; l < 3; ++l) {
        const float* Wg = (const float*)d_in[10 + 4 * l];
        const float* bg = (const float*)d_in[11 + 4 * l];
        const float* gm = (const float*)d_in[12 + 4 * l];
        const float* bt = (const float*)d_in[13 + 4 * l];
        gcn_gemm<<<(NN + 31) / 32, 256, 0, stream>>>(h, Wg, hw);
        gcn_agg<<<NN / 2, 256, 0, stream>>>(hw, off, crow, cw, dinv, bg, gm, bt, h);
    }

    hipMemsetAsync(pooled, 0, HH * sizeof(float), stream);
    pool_k<<<256, 256, 0, stream>>>(h, pooled);
    final_k<<<1, 64, 0, stream>>>(pooled, Wout, bout, out);
}

// Round 4
// 7871.772 us; speedup vs baseline: 4.2316x; 1.8996x over previous
//
#include <hip/hip_runtime.h>

// Problem constants (fixed by the reference)
#define NN 50000
#define TT 200
#define HH 128
#define EE 1600000

typedef _Float16 f16x8 __attribute__((ext_vector_type(8)));
typedef float f32x4 __attribute__((ext_vector_type(4)));

__device__ __forceinline__ float sigf(float x) {
    return __builtin_amdgcn_rcpf(1.f + __expf(-x));
}
__device__ __forceinline__ float tanhf_(float x) {
    return 1.f - 2.f * __builtin_amdgcn_rcpf(__expf(2.f * x) + 1.f);
}
__device__ __forceinline__ f32x4 sig4(f32x4 x) {
    f32x4 r; r[0] = sigf(x[0]); r[1] = sigf(x[1]); r[2] = sigf(x[2]); r[3] = sigf(x[3]); return r;
}
__device__ __forceinline__ f32x4 tanh4(f32x4 x) {
    f32x4 r; r[0] = tanhf_(x[0]); r[1] = tanhf_(x[1]); r[2] = tanhf_(x[2]); r[3] = tanhf_(x[3]); return r;
}
__device__ __forceinline__ f32x4 splat4(float s) { f32x4 r = {s, s, s, s}; return r; }
__device__ __forceinline__ unsigned short f2h_bits(float x) {
    _Float16 h = (_Float16)x;
    union { _Float16 h; unsigned short u; } cv; cv.h = h; return cv.u;
}
__device__ __forceinline__ float h2f_bits(unsigned short u) {
    union { _Float16 h; unsigned short u; } cv; cv.u = u; return (float)cv.h;
}

// ---------------------------------------------------------------------------
// Weight packing: W is (512,128) row-major (PyTorch [4H, H]).
// MFMA-16x16x32 B-fragment order: tile jn (0..31 over gate-cols), chunk kk (0..3):
// out[(jn*4+kk)*512 + L*8 + i] = W[jn*16 + (L&15)][kk*32 + (L>>4)*8 + i]  (f16)
// ---------------------------------------------------------------------------
__global__ void pack_w(const float* __restrict__ W, unsigned short* __restrict__ out) {
    int tile = blockIdx.x;          // jn*4 + kk
    int jn = tile >> 2, kk = tile & 3;
    int L = threadIdx.x;            // 0..63
    int n = jn * 16 + (L & 15);
    int k0 = kk * 32 + (L >> 4) * 8;
    unsigned short* dst = out + (size_t)tile * 512 + L * 8;
#pragma unroll
    for (int i = 0; i < 8; ++i) dst[i] = f2h_bits(W[n * 128 + k0 + i]);
}

__global__ void bias_prep(const float* __restrict__ bih0, const float* __restrict__ bhh0,
                          const float* __restrict__ bih1, const float* __restrict__ bhh1,
                          const float* __restrict__ wih0,
                          float* __restrict__ b0g, float* __restrict__ b1g, float* __restrict__ wxg) {
    int i = blockIdx.x * 256 + threadIdx.x;
    if (i < 512) {
        b0g[i] = bih0[i] + bhh0[i];
        b1g[i] = bih1[i] + bhh1[i];
        wxg[i] = wih0[i];
    }
}

// lightcurve [N][T] -> xT [T][N]
__global__ void transpose_lc(const float* __restrict__ lc, float* __restrict__ xT) {
    __shared__ float tile[32][33];
    int tx = threadIdx.x, ty = threadIdx.y;    // 32 x 8
    int n0 = blockIdx.y * 32, t0 = blockIdx.x * 32;
#pragma unroll
    for (int i = 0; i < 32; i += 8) {
        int n = n0 + ty + i, t = t0 + tx;
        if (n < NN && t < TT) tile[ty + i][tx] = lc[(size_t)n * TT + t];
    }
    __syncthreads();
#pragma unroll
    for (int i = 0; i < 32; i += 8) {
        int t = t0 + ty + i, n = n0 + tx;
        if (n < NN && t < TT) xT[(size_t)t * NN + n] = tile[tx][ty + i];
    }
}

// ---------------------------------------------------------------------------
// Fused 2-layer LSTM. Block = 512 threads (8 waves), 32 nodes, 200 steps.
// Wave u owns col-group jt=u: 16 hidden cols x 4 gates x 32 rows.
// Per-lane state: 32 acc + 16 c + small transients -> no spill.
// h states double-buffered in LDS (f16): 2 barriers/step. c in VGPRs (fp32).
// ---------------------------------------------------------------------------

#define MFMA16(A, B, C) __builtin_amdgcn_mfma_f32_16x16x32_f16((A), (B), (C), 0, 0, 0)

// One 32-wide K-chunk: 4 B-frags (gates), 2 A-frags (row tiles), 8 MFMAs
#define MMC(HB, PI, PF, PG, PO, KK) {                                          \
    f16x8 bI_ = *reinterpret_cast<const f16x8*>((PI) + (KK) * 512);            \
    f16x8 bF_ = *reinterpret_cast<const f16x8*>((PF) + (KK) * 512);            \
    f16x8 bG_ = *reinterpret_cast<const f16x8*>((PG) + (KK) * 512);            \
    f16x8 bO_ = *reinterpret_cast<const f16x8*>((PO) + (KK) * 512);            \
    f16x8 a0_ = *reinterpret_cast<const f16x8*>(&(HB)[col][(KK) * 32 + quad * 8]);      \
    f16x8 a1_ = *reinterpret_cast<const f16x8*>(&(HB)[16 + col][(KK) * 32 + quad * 8]); \
    aI0 = MFMA16(a0_, bI_, aI0); aI1 = MFMA16(a1_, bI_, aI1);                  \
    aF0 = MFMA16(a0_, bF_, aF0); aF1 = MFMA16(a1_, bF_, aF1);                  \
    aG0 = MFMA16(a0_, bG_, aG0); aG1 = MFMA16(a1_, bG_, aG1);                  \
    aO0 = MFMA16(a0_, bO_, aO0); aO1 = MFMA16(a1_, bO_, aO1);                  \
}

// Activation with x*w_ih terms (layer 0), rowtile RT (rows RT*16+quad*4 ..+3)
#define ACT0N(RT, C, H, AI, AF, AG, AO) {                                      \
    f32x4 xv_ = *reinterpret_cast<const f32x4*>(&xs[(RT) * 16 + quad * 4]);    \
    f32x4 gi_ = AI + splat4(bI) + xv_ * splat4(wI);                            \
    f32x4 gf_ = AF + splat4(bF) + xv_ * splat4(wF);                            \
    f32x4 gg_ = AG + splat4(bG) + xv_ * splat4(wG);                            \
    f32x4 go_ = AO + splat4(bO) + xv_ * splat4(wO);                            \
    C = sig4(gf_) * C + sig4(gi_) * tanh4(gg_);                                \
    H = sig4(go_) * tanh4(C);                                                  \
}

// Activation, no x terms (layer 1)
#define ACT1N(C, H, AI, AF, AG, AO) {                                          \
    f32x4 gi_ = AI + splat4(bI);                                               \
    f32x4 gf_ = AF + splat4(bF);                                               \
    f32x4 gg_ = AG + splat4(bG);                                               \
    f32x4 go_ = AO + splat4(bO);                                               \
    C = sig4(gf_) * C + sig4(gi_) * tanh4(gg_);                                \
    H = sig4(go_) * tanh4(C);                                                  \
}

// Write rowtile RT of this wave's h (f16) into LDS buffer
#define WRH(HB, RT, H)                                                         \
    (HB)[(RT) * 16 + quad * 4 + 0][j_] = f2h_bits((H)[0]);                     \
    (HB)[(RT) * 16 + quad * 4 + 1][j_] = f2h_bits((H)[1]);                     \
    (HB)[(RT) * 16 + quad * 4 + 2][j_] = f2h_bits((H)[2]);                     \
    (HB)[(RT) * 16 + quad * 4 + 3][j_] = f2h_bits((H)[3]);

// One timestep: PB = write buffer (t&1), RB = read buffer (PB^1)
#define STEP(PB, RB, T)                                                        \
    {   /* layer 0: gates = h1_old @ Whh0^T + x*wih0 + b0 */                   \
        f32x4 aI0 = {}, aI1 = {}, aF0 = {}, aF1 = {};                          \
        f32x4 aG0 = {}, aG1 = {}, aO0 = {}, aO1 = {};                          \
        MMC(h1s[RB], p0I, p0F, p0G, p0O, 0)                                    \
        MMC(h1s[RB], p0I, p0F, p0G, p0O, 1)                                    \
        MMC(h1s[RB], p0I, p0F, p0G, p0O, 2)                                    \
        MMC(h1s[RB], p0I, p0F, p0G, p0O, 3)                                    \
        const float bI = b0s[j_], bF = b0s[128 + j_];                          \
        const float bG = b0s[256 + j_], bO = b0s[384 + j_];                    \
        const float wI = wxs[j_], wF = wxs[128 + j_];                          \
        const float wG = wxs[256 + j_], wO = wxs[384 + j_];                    \
        f32x4 h1v0, h1v1;                                                      \
        ACT0N(0, c1_0, h1v0, aI0, aF0, aG0, aO0)                               \
        ACT0N(1, c1_1, h1v1, aI1, aF1, aG1, aO1)                               \
        WRH(h1s[PB], 0, h1v0)                                                  \
        WRH(h1s[PB], 1, h1v1)                                                  \
    }                                                                          \
    __syncthreads();                                                           \
    {   /* layer 1: gates = h1_new @ Wih1^T + h2_old @ Whh1^T + b1 */          \
        f32x4 aI0 = {}, aI1 = {}, aF0 = {}, aF1 = {};                          \
        f32x4 aG0 = {}, aG1 = {}, aO0 = {}, aO1 = {};                          \
        MMC(h1s[PB], u0I, u0F, u0G, u0O, 0)                                    \
        MMC(h1s[PB], u0I, u0F, u0G, u0O, 1)                                    \
        MMC(h1s[PB], u0I, u0F, u0G, u0O, 2)                                    \
        MMC(h1s[PB], u0I, u0F, u0G, u0O, 3)                                    \
        MMC(h2s[RB], v0I, v0F, v0G, v0O, 0)                                    \
        MMC(h2s[RB], v0I, v0F, v0G, v0O, 1)                                    \
        MMC(h2s[RB], v0I, v0F, v0G, v0O, 2)                                    \
        MMC(h2s[RB], v0I, v0F, v0G, v0O, 3)                                    \
        const float bI = b1s[j_], bF = b1s[128 + j_];                          \
        const float bG = b1s[256 + j_], bO = b1s[384 + j_];                    \
        f32x4 h2v0, h2v1;                                                      \
        ACT1N(c2_0, h2v0, aI0, aF0, aG0, aO0)                                  \
        ACT1N(c2_1, h2v1, aI1, aF1, aG1, aO1)                                  \
        WRH(h2s[PB], 0, h2v0)                                                  \
        WRH(h2s[PB], 1, h2v1)                                                  \
        if (tid < 32) {                                                        \
            int n_ = n0 + tid;                                                 \
            xs[tid] = ((T) + 1 < TT && n_ < NN)                                \
                          ? xT[(size_t)((T) + 1) * NN + n_] : 0.f;             \
        }                                                                      \
    }                                                                          \
    __syncthreads();

__global__ __launch_bounds__(512, 2) void lstm_kernel(
    const float* __restrict__ xT,
    const unsigned short* __restrict__ w0p,
    const unsigned short* __restrict__ w1ip,
    const unsigned short* __restrict__ w1hp,
    const float* __restrict__ b0g, const float* __restrict__ b1g,
    const float* __restrict__ wxg,
    float* __restrict__ h2out) {
    __shared__ unsigned short h1s[2][32][136];   // double-buffered, f16
    __shared__ unsigned short h2s[2][32][136];
    __shared__ __align__(16) float xs[32];
    __shared__ float b0s[512], b1s[512], wxs[512];

    const int tid = threadIdx.x;
    const int w = tid >> 6;          // wave id 0..7 == col-group jt
    const int lane = tid & 63;
    const int col = lane & 15;
    const int quad = lane >> 4;
    const int n0 = blockIdx.x * 32;
    const int j_ = w * 16 + col;     // this lane's hidden column

    for (int i = tid; i < 2 * 32 * 136; i += 512) {
        (&h1s[0][0][0])[i] = 0; (&h2s[0][0][0])[i] = 0;
    }
    if (tid < 512) { b0s[tid] = b0g[tid]; b1s[tid] = b1g[tid]; wxs[tid] = wxg[tid]; }
    if (tid < 32) { int n = n0 + tid; xs[tid] = (n < NN) ? xT[n] : 0.f; }

    // B-fragment base pointers (gate g tile = 8g + jt; tile stride 2048 ushorts)
    const unsigned short* p0I = w0p + (size_t)w * 2048 + lane * 8;
    const unsigned short* p0F = w0p + (size_t)(8 + w) * 2048 + lane * 8;
    const unsigned short* p0G = w0p + (size_t)(16 + w) * 2048 + lane * 8;
    const unsigned short* p0O = w0p + (size_t)(24 + w) * 2048 + lane * 8;
    const unsigned short* u0I = w1ip + (size_t)w * 2048 + lane * 8;
    const unsigned short* u0F = w1ip + (size_t)(8 + w) * 2048 + lane * 8;
    const unsigned short* u0G = w1ip + (size_t)(16 + w) * 2048 + lane * 8;
    const unsigned short* u0O = w1ip + (size_t)(24 + w) * 2048 + lane * 8;
    const unsigned short* v0I = w1hp + (size_t)w * 2048 + lane * 8;
    const unsigned short* v0F = w1hp + (size_t)(8 + w) * 2048 + lane * 8;
    const unsigned short* v0G = w1hp + (size_t)(16 + w) * 2048 + lane * 8;
    const unsigned short* v0O = w1hp + (size_t)(24 + w) * 2048 + lane * 8;

    // persistent cell state: 4 f32x4 = 16 regs
    f32x4 c1_0 = {}, c1_1 = {}, c2_0 = {}, c2_1 = {};

    __syncthreads();

#pragma unroll 1
    for (int tt = 0; tt < TT; tt += 2) {
        STEP(0, 1, tt)
        STEP(1, 0, tt + 1)
    }

    // final h2 lives in buffer 1 (last step wrote PB=1); cooperative write-out
    for (int i = tid; i < 32 * 128; i += 512) {
        int m = i >> 7, j = i & 127;
        int n = n0 + m;
        if (n < NN) h2out[(size_t)n * HH + j] = h2f_bits(h2s[1][m][j]);
    }
}

// ---------------------------------------------------------------------------
// GCN pieces (fp32)
// ---------------------------------------------------------------------------
__global__ void deg_init(float* __restrict__ deg) {
    int i = blockIdx.x * 256 + threadIdx.x;
    if (i < NN) deg[i] = 1.f;   // self loop
}
__global__ void deg_edges(const int* __restrict__ ei, float* __restrict__ deg) {
    int e = blockIdx.x * 256 + threadIdx.x;
    if (e < EE) unsafeAtomicAdd(&deg[ei[EE + e]], 1.f);   // col = target
}
__global__ void dinv_k(const float* __restrict__ deg, float* __restrict__ dinv) {
    int i = blockIdx.x * 256 + threadIdx.x;
    if (i < NN) dinv[i] = rsqrtf(fmaxf(deg[i], 1.f));
}

// exclusive scan of per-node in-edge counts (deg-1) -> off[0..NN]
__global__ void scan_off(const float* __restrict__ deg, int* __restrict__ off) {
    __shared__ int sp[256];
    const int tid = threadIdx.x;
    const int chunk = (NN + 255) / 256;
    const int i0 = tid * chunk;
    int s = 0;
    for (int i = 0; i < chunk; ++i) {
        int idx = i0 + i;
        if (idx < NN) s += (int)deg[idx] - 1;
    }
    sp[tid] = s;
    __syncthreads();
    for (int o = 1; o < 256; o <<= 1) {
        int v = (tid >= o) ? sp[tid - o] : 0;
        __syncthreads();
        sp[tid] += v;
        __syncthreads();
    }
    int run = sp[tid] - s;
    for (int i = 0; i < chunk; ++i) {
        int idx = i0 + i;
        if (idx < NN) { off[idx] = run; run += (int)deg[idx] - 1; }
    }
    if (tid == 255) off[NN] = sp[255];
}

__global__ void csr_fill(const int* __restrict__ ei, const float* __restrict__ dinv,
                         const int* __restrict__ off, int* __restrict__ cur,
                         int* __restrict__ crow, float* __restrict__ cw) {
    int e = blockIdx.x * 256 + threadIdx.x;
    if (e >= EE) return;
    int r = ei[e], c = ei[EE + e];
    int p = atomicAdd(&cur[c], 1);
    int idx = off[c] + p;
    crow[idx] = r;
    cw[idx] = dinv[r] * dinv[c];
}

// hw = h @ Wg   ([N,128] x [128,128]); 32 nodes per block
__global__ void gcn_gemm(const float* __restrict__ h, const float* __restrict__ Wg,
                         float* __restrict__ hw) {
    __shared__ float hsT[128][36];
    int tid = threadIdx.x;
    int n0 = blockIdx.x * 32;
#pragma unroll
    for (int c = 0; c < 16; ++c) {
        int lin = c * 256 + tid;
        int m = lin >> 7, k = lin & 127;
        int n = n0 + m;
        hsT[k][m] = (n < NN) ? h[(size_t)n * HH + k] : 0.f;
    }
    __syncthreads();
    int j = tid & 127, p = tid >> 7;
    float acc[16];
#pragma unroll
    for (int m = 0; m < 16; ++m) acc[m] = 0.f;
    for (int k = 0; k < 128; ++k) {
        float wg = Wg[k * 128 + j];
        const float4* hp = reinterpret_cast<const float4*>(&hsT[k][p * 16]);
        float4 a = hp[0], b = hp[1], c = hp[2], d = hp[3];
        acc[0]  += a.x * wg; acc[1]  += a.y * wg; acc[2]  += a.z * wg; acc[3]  += a.w * wg;
        acc[4]  += b.x * wg; acc[5]  += b.y * wg; acc[6]  += b.z * wg; acc[7]  += b.w * wg;
        acc[8]  += c.x * wg; acc[9]  += c.y * wg; acc[10] += c.z * wg; acc[11] += c.w * wg;
        acc[12] += d.x * wg; acc[13] += d.y * wg; acc[14] += d.z * wg; acc[15] += d.w * wg;
    }
#pragma unroll
    for (int m = 0; m < 16; ++m) {
        int n = n0 + p * 16 + m;
        if (n < NN) hw[(size_t)n * HH + j] = acc[m];
    }
}

// Fused: self-loop + CSR gather + bias + LayerNorm + ReLU + residual
__global__ __launch_bounds__(256) void gcn_agg(
    const float* __restrict__ hw, const int* __restrict__ off,
    const int* __restrict__ crow, const float* __restrict__ cw,
    const float* __restrict__ dinv, const float* __restrict__ bg,
    const float* __restrict__ gamma, const float* __restrict__ beta,
    float* __restrict__ h) {
    __shared__ float xch[4][2];
    const int tid = threadIdx.x;
    const int half = tid >> 7;
    const int f = tid & 127;
    const int v = blockIdx.x * 2 + half;
    const float d = dinv[v];
    float acc = bg[f] + d * d * hw[v * HH + f];
    const int s1 = off[v + 1];
    for (int s = off[v]; s < s1; ++s) {
        int r = crow[s];
        float wv = cw[s];
        acc = fmaf(wv, hw[r * HH + f], acc);
    }
    float sum = acc, sq = acc * acc;
#pragma unroll
    for (int o = 32; o; o >>= 1) { sum += __shfl_xor(sum, o); sq += __shfl_xor(sq, o); }
    int wid = tid >> 6;
    if ((tid & 63) == 0) { xch[wid][0] = sum; xch[wid][1] = sq; }
    __syncthreads();
    sum += xch[wid ^ 1][0]; sq += xch[wid ^ 1][1];
    float mu = sum * (1.f / 128.f);
    float var = sq * (1.f / 128.f) - mu * mu;
    float rn = rsqrtf(var + 1e-5f);
    float o = (acc - mu) * rn * gamma[f] + beta[f];
    h[v * HH + f] = fmaxf(o, 0.f) + h[v * HH + f];
}

__global__ void pool_k(const float* __restrict__ h, float* __restrict__ pooled) {
    int j = threadIdx.x & 127, p = threadIdx.x >> 7;
    float s = 0.f;
    for (int n = blockIdx.x * 2 + p; n < NN; n += 512) s += h[(size_t)n * HH + j];
    unsafeAtomicAdd(&pooled[j], s);
}

__global__ void final_k(const float* __restrict__ pooled, const float* __restrict__ Wout,
                        const float* __restrict__ bout, float* __restrict__ out) {
    int lane = threadIdx.x;
    float s = pooled[lane] * Wout[lane] + pooled[lane + 64] * Wout[lane + 64];
#pragma unroll
    for (int o = 32; o; o >>= 1) s += __shfl_xor(s, o);
    if (lane == 0) out[0] = s * (1.f / (float)NN) + bout[0];
}

// ---------------------------------------------------------------------------
extern "C" void kernel_launch(void* const* d_in, const int* in_sizes, int n_in,
                              void* d_out, int out_size, void* d_ws, size_t ws_size,
                              hipStream_t stream) {
    const float* lc   = (const float*)d_in[0];
    const int*   ei   = (const int*)d_in[1];
    const float* Wih0 = (const float*)d_in[2];
    const float* Whh0 = (const float*)d_in[3];
    const float* bih0 = (const float*)d_in[4];
    const float* bhh0 = (const float*)d_in[5];
    const float* Wih1 = (const float*)d_in[6];
    const float* Whh1 = (const float*)d_in[7];
    const float* bih1 = (const float*)d_in[8];
    const float* bhh1 = (const float*)d_in[9];
    const float* Wout = (const float*)d_in[22];
    const float* bout = (const float*)d_in[23];
    float* out = (float*)d_out;

    float* ws   = (float*)d_ws;
    float* h    = ws;
    float* hw   = ws + 6400000;
    float* xT   = ws + 6400000;                    // aliases hw+CSR region pre-LSTM
    int*   off  = (int*)(ws + 12800000);
    int*   cur  = off + 50048;
    int*   crow = cur + 50048;
    float* cw   = (float*)(crow + EE);
    float* P      = ws + 16400064;
    float* deg    = P;
    float* dinv   = deg + 50000;
    float* b0g    = dinv + 50000;
    float* b1g    = b0g + 512;
    float* wxg    = b1g + 512;
    float* pooled = wxg + 512;
    unsigned short* w0p  = (unsigned short*)(pooled + 128);
    unsigned short* w1ip = w0p + 65536;
    unsigned short* w1hp = w1ip + 65536;

    pack_w<<<128, 64, 0, stream>>>(Whh0, w0p);
    pack_w<<<128, 64, 0, stream>>>(Wih1, w1ip);
    pack_w<<<128, 64, 0, stream>>>(Whh1, w1hp);
    bias_prep<<<2, 256, 0, stream>>>(bih0, bhh0, bih1, bhh1, Wih0, b0g, b1g, wxg);
    {
        dim3 g((TT + 31) / 32, (NN + 31) / 32), b(32, 8);
        transpose_lc<<<g, b, 0, stream>>>(lc, xT);
    }
    deg_init<<<(NN + 255) / 256, 256, 0, stream>>>(deg);
    deg_edges<<<(EE + 255) / 256, 256, 0, stream>>>(ei, deg);
    dinv_k<<<(NN + 255) / 256, 256, 0, stream>>>(deg, dinv);

    lstm_kernel<<<(NN + 31) / 32, 512, 0, stream>>>(xT, w0p, w1ip, w1hp, b0g, b1g, wxg, h);

    hipMemsetAsync(cur, 0, 50000 * sizeof(int), stream);
    scan_off<<<1, 256, 0, stream>>>(deg, off);
    csr_fill<<<(EE + 255) / 256, 256, 0, stream>>>(ei, dinv, off, cur, crow, cw);

    for (int l = 0; l < 3; ++l) {
        const float* Wg = (const float*)d_in[10 + 4 * l];
        const float* bg = (const float*)d_in[11 + 4 * l];
        const float* gm = (const float*)d_in[12 + 4 * l];
        const float* bt = (const float*)d_in[13 + 4 * l];
        gcn_gemm<<<(NN + 31) / 32, 256, 0, stream>>>(h, Wg, hw);
        gcn_agg<<<NN / 2, 256, 0, stream>>>(hw, off, crow, cw, dinv, bg, gm, bt, h);
    }

    hipMemsetAsync(pooled, 0, HH * sizeof(float), stream);
    pool_k<<<256, 256, 0, stream>>>(h, pooled);
    final_k<<<1, 64, 0, stream>>>(pooled, Wout, bout, out);
}